// Round 14
// baseline (284.081 us; speedup 1.0000x reference)
//
#include <hip/hip_runtime.h>
#include <math.h>

// Problem constants
#define T      2048
#define HIDDEN 2048
#define NH     32
#define NKV    4
#define D      128
#define WINDOW 512
#define QKVW   ((NH + 2 * NKV) * D)   // 5120
#define ODIM   (NH * D)               // 4096
#define EPS    1e-6f
#define SCALE  0.08838834764831845f   // D^-0.5
#define PSTR   68                     // attn P-slab stride (validated R5)
#define ESTR   136                    // Q/K epilogue slab stride (16B-aligned rows)
#define VSTR   36                     // V epilogue slab stride (8B-aligned)
#define QMUL   ((float)(0.08838834764831845 * 1.4426950408889634))
#define MLOG2E 5.7707801635558536f    // 4.0*log2(e); |score|<=11.3 (Cauchy-Schwarz)

typedef _Float16 f16x8 __attribute__((ext_vector_type(8)));
typedef _Float16 f16x4 __attribute__((ext_vector_type(4)));
typedef float    f32x4 __attribute__((ext_vector_type(4)));

// ---------------------------------------------------------------------------
// Packed fragment format (validated R2-R6):
// chunk c = q*16 + o (q=c>>4, o=c&15), chunk = 8 k-consecutive f16 at outer o.
// A-operand: lane holds A[m=lane&15][k=(lane>>4)*8+j]
// B-operand: lane holds B[k=(lane>>4)*8+j][n=lane&15]
// ---------------------------------------------------------------------------

__device__ __forceinline__ void gl2lds16(const void* g, void* l) {
  __builtin_amdgcn_global_load_lds((const __attribute__((address_space(1))) void*)g,
                                   (__attribute__((address_space(3))) void*)l,
                                   16, 0, 0);
}

// ---------------------------------------------------------------------------
// prep: all input packing + RoPE tables in ONE dispatch (block-range branch).
// ---------------------------------------------------------------------------
#define NB_A  2048
#define NB_B1 5120
#define NB_B2 4096
__global__ __launch_bounds__(256)
void prep(const float* __restrict__ hidden, const float* __restrict__ w_qkv,
          const float* __restrict__ w_o, const int* __restrict__ positions,
          _Float16* __restrict__ Ah1, _Float16* __restrict__ Bp1,
          _Float16* __restrict__ Bp2, float* __restrict__ cosT,
          float* __restrict__ sinT) {
  const int bx = blockIdx.x;
  const int tid = threadIdx.x;
  if (bx < NB_A) {
    // pack A: hidden [T][HIDDEN] -> A-frag chunks
    const int cid = bx * 256 + tid;
    const int c = cid & 63;
    const int tile = cid >> 6;
    const int mtg = tile & (T / 16 - 1);
    const int kt = tile >> 7;
    const float* src = hidden + (size_t)(mtg * 16 + (c & 15)) * HIDDEN + kt * 32 + (c >> 4) * 8;
    const float4 a = *(const float4*)src;
    const float4 b = *(const float4*)(src + 4);
    f16x8 h;
    h[0] = (_Float16)a.x; h[1] = (_Float16)a.y; h[2] = (_Float16)a.z; h[3] = (_Float16)a.w;
    h[4] = (_Float16)b.x; h[5] = (_Float16)b.y; h[6] = (_Float16)b.z; h[7] = (_Float16)b.w;
    *(f16x8*)(Ah1 + (size_t)cid * 8) = h;
  } else if (bx < NB_A + NB_B1) {
    // pack B: w_qkv [HIDDEN][QKVW]
    const int cid = (bx - NB_A) * 256 + tid;
    const int c = cid & 63;
    const int tile = cid >> 6;
    const int ntg = tile % (QKVW >> 4);
    const int kt = tile / (QKVW >> 4);
    const float* src = w_qkv + (size_t)(kt * 32 + (c >> 4) * 8) * QKVW + ntg * 16 + (c & 15);
    f16x8 h;
#pragma unroll
    for (int j = 0; j < 8; ++j) h[j] = (_Float16)src[(size_t)j * QKVW];
    *(f16x8*)(Bp1 + (size_t)cid * 8) = h;
  } else if (bx < NB_A + NB_B1 + NB_B2) {
    // pack B: w_o [ODIM][HIDDEN]
    const int cid = (bx - NB_A - NB_B1) * 256 + tid;
    const int c = cid & 63;
    const int tile = cid >> 6;
    const int ntg = tile & (HIDDEN / 16 - 1);
    const int kt = tile >> 7;
    const float* src = w_o + (size_t)(kt * 32 + (c >> 4) * 8) * HIDDEN + ntg * 16 + (c & 15);
    f16x8 h;
#pragma unroll
    for (int j = 0; j < 8; ++j) h[j] = (_Float16)src[(size_t)j * HIDDEN];
    *(f16x8*)(Bp2 + (size_t)cid * 8) = h;
  } else {
    // RoPE tables: 64 positions per block
    const int p0 = (bx - NB_A - NB_B1 - NB_B2) * 64 + (tid >> 6) * 16;
    const int j = tid & 63;
    const float invf = (float)pow(1.0e6, -(double)j / 64.0);
#pragma unroll 4
    for (int i = 0; i < 16; ++i) {
      const int t = p0 + i;
      const float ang = (float)positions[t] * invf;
      cosT[t * 64 + j] = cosf(ang);
      sinT[t * 64 + j] = sinf(ang);
    }
  }
}

// ---------------------------------------------------------------------------
// gemm1 fused (R15 = R12-validated ring-3, 59.7us): 128x128 tile, 4 waves,
// ring-3 counted-vmcnt(4), 48KB -> 3 blocks/CU. R14's ring-4 measured WORSE
// (72.7us, occupancy 24->13%): at 64KB only 2 blocks/CU fit and the lost TLP
// outweighed prefetch depth. For this kernel occupancy > pipeline depth.
// ---------------------------------------------------------------------------
#define KSTEPS 64   // HIDDEN / 32

__global__ __launch_bounds__(256, 3)
void gemm_qkv(const _Float16* __restrict__ Apk, const _Float16* __restrict__ Bpk,
              const float* __restrict__ qnw, const float* __restrict__ knw,
              const float* __restrict__ cosT, const float* __restrict__ sinT,
              _Float16* __restrict__ Qpk, _Float16* __restrict__ Kpk,
              _Float16* __restrict__ Vpk) {
  extern __shared__ _Float16 SM[];
  const int tid = threadIdx.x;
  const int lane = tid & 63;
  const int wv = tid >> 6;       // 0..3; wave owns rows wv*32..+32
  const int l15 = lane & 15;
  const int l4 = lane >> 4;
  const int bx = blockIdx.x, by = blockIdx.y;

  f32x4 acc[2][8];
#pragma unroll
  for (int i = 0; i < 2; ++i)
#pragma unroll
    for (int j = 0; j < 8; ++j) acc[i][j] = (f32x4)0.f;

  // staging: 16 units (A:8 row-tiles + B:8 col-tiles) / 4 waves = 4 per wave
  auto stage = [&](int k, int s) {
    const int u = wv * 4 + s;
    char* dst = (char*)SM + (k % 3) * 16384 +
                (u < 8 ? u * 1024 : 8192 + (u - 8) * 1024);
    const char* src = (u < 8)
        ? (const char*)Apk + ((size_t)k * (T / 16) + by * 8 + u) * 1024 + lane * 16
        : (const char*)Bpk + ((size_t)k * (QKVW / 16) + bx * 8 + (u - 8)) * 1024 + lane * 16;
    gl2lds16(src, dst);
  };

  // prologue: stage k = 0,1 ; wait for k=0 (4 younger stay in flight)
#pragma unroll
  for (int k = 0; k < 2; ++k)
#pragma unroll
    for (int s = 0; s < 4; ++s) stage(k, s);
  asm volatile("s_waitcnt vmcnt(4)" ::: "memory");
  __builtin_amdgcn_s_barrier();
  __builtin_amdgcn_sched_barrier(0);

  int slot = 0;
  for (int t = 0; t < KSTEPS; ++t) {
    const _Float16* As = SM + slot * 8192;
    const _Float16* Bs = As + 4096;
    f16x8 af[2], bf[8];
#pragma unroll
    for (int i = 0; i < 2; ++i)
      af[i] = *(const f16x8*)(As + (wv * 2 + i) * 512 + lane * 8);
#pragma unroll
    for (int j = 0; j < 8; ++j)
      bf[j] = *(const f16x8*)(Bs + j * 512 + lane * 8);
    // prefetch k = t+2 into the slot freed at the end of step t-1
    if (t + 2 < KSTEPS)
#pragma unroll
      for (int s = 0; s < 4; ++s) stage(t + 2, s);
    __builtin_amdgcn_s_setprio(1);
#pragma unroll
    for (int i = 0; i < 2; ++i)
#pragma unroll
      for (int j = 0; j < 8; ++j)
        acc[i][j] = __builtin_amdgcn_mfma_f32_16x16x32_f16(af[i], bf[j], acc[i][j], 0, 0, 0);
    __builtin_amdgcn_s_setprio(0);
    // boundary: counted wait -> next step's slot fully staged
    if (t < KSTEPS - 2)       asm volatile("s_waitcnt vmcnt(4)" ::: "memory");
    else if (t == KSTEPS - 2) asm volatile("s_waitcnt vmcnt(0)" ::: "memory");
    __builtin_amdgcn_s_barrier();
    __builtin_amdgcn_sched_barrier(0);
    slot = (slot == 2) ? 0 : slot + 1;
  }
  __syncthreads();   // fence staging before epilogue slab reuse

  // ---- fused epilogue (validated R2-R6, byte-identical indexing) ----
  if (bx < NH + NKV) {
    const bool isq = bx < NH;
    const float* w = isq ? qnw : knw;
    const float omul = isq ? QMUL : 1.0f;
    float wcol[8];
#pragma unroll
    for (int j = 0; j < 8; ++j) wcol[j] = w[j * 16 + l15];

    _Float16* ex = SM + wv * (32 * ESTR);   // wave-private 32 x 136
#pragma unroll
    for (int i = 0; i < 2; ++i)
#pragma unroll
      for (int r = 0; r < 4; ++r) {
        float ss = 0.f;
#pragma unroll
        for (int j = 0; j < 8; ++j) ss += acc[i][j][r] * acc[i][j][r];
        ss += __shfl_xor(ss, 1); ss += __shfl_xor(ss, 2);
        ss += __shfl_xor(ss, 4); ss += __shfl_xor(ss, 8);
        const float rn = 1.0f / sqrtf(ss * (1.0f / D) + EPS);
        const int row = i * 16 + l4 * 4 + r;
        const int t = by * 128 + wv * 32 + row;
#pragma unroll
        for (int j = 0; j < 4; ++j) {
          const int jc = j * 16 + l15;
          const float c = cosT[t * 64 + jc];
          const float s = sinT[t * 64 + jc];
          const float x1 = acc[i][j][r] * rn * wcol[j];
          const float x2 = acc[i][j + 4][r] * rn * wcol[j + 4];
          ex[row * ESTR + jc]      = (_Float16)((x1 * c - x2 * s) * omul);
          ex[row * ESTR + 64 + jc] = (_Float16)((x2 * c + x1 * s) * omul);
        }
      }
    // read back in A-frag order (in-wave lgkmcnt ordering, no barrier)
    const int hl = isq ? bx : bx - NH;
    _Float16* dst0 = isq ? Qpk : Kpk;
#pragma unroll
    for (int u = 0; u < 2; ++u) {
      const int qt = by * 8 + wv * 2 + u;
#pragma unroll
      for (int ds = 0; ds < 4; ++ds) {
        const f16x8 frag = *(const f16x8*)(ex + (u * 16 + l15) * ESTR + ds * 32 + l4 * 8);
        *(f16x8*)(dst0 + ((size_t)(hl * 128 + qt) * 4 + ds) * 512 + lane * 8) = frag;
      }
    }
  } else {
    // V: cast + transpose to validated Vpk B-operand layout, wave-private
    const int kvh = bx - NH - NKV;
    _Float16* exv = SM + wv * (128 * VSTR);  // [d 0..127][local key 0..31]
#pragma unroll
    for (int i = 0; i < 2; ++i)
#pragma unroll
      for (int j = 0; j < 8; ++j) {
        f16x4 v4;
#pragma unroll
        for (int r = 0; r < 4; ++r) v4[r] = (_Float16)acc[i][j][r];
        *(f16x4*)(exv + (j * 16 + l15) * VSTR + i * 16 + l4 * 4) = v4;
      }
    const int kt64 = by * 2 + (wv >> 1);
    const int ks = wv & 1;
#pragma unroll
    for (int dt = 0; dt < 8; ++dt) {
      const f16x4 lo = *(const f16x4*)(exv + (dt * 16 + l15) * VSTR + l4 * 8);
      const f16x4 hi = *(const f16x4*)(exv + (dt * 16 + l15) * VSTR + l4 * 8 + 4);
      f16x8 h8;
#pragma unroll
      for (int r = 0; r < 4; ++r) { h8[r] = lo[r]; h8[r + 4] = hi[r]; }
      *(f16x8*)(Vpk + (((size_t)(kvh * 32 + kt64) * 2 + ks) * 8 + dt) * 512 + lane * 8) = h8;
    }
  }
}

// ---------------------------------------------------------------------------
// gemm2 (R14 ring-4, kept): grid 512 = exactly 2 blocks/CU, so ring-4's
// 2/CU LDS cap costs nothing and the deeper prefetch helped (~8us inferred
// from R14 totals: total +4.6 while gemm_qkv +13 -> f16p -8.4).
// ---------------------------------------------------------------------------
__global__ __launch_bounds__(256, 2)
void gemm_f16p(const _Float16* __restrict__ Apk, const _Float16* __restrict__ Bpk,
               float* __restrict__ C0, float* __restrict__ C1,
               int M, int N, int nkt) {
  extern __shared__ _Float16 SM[];
  const int tid = threadIdx.x;
  const int lane = tid & 63;
  const int wv = tid >> 6;
  const int wr = wv & 1, wc = wv >> 1;
  const int kt0 = blockIdx.z * nkt;
  float* __restrict__ C = blockIdx.z ? C1 : C0;

  f32x4 acc[4][4];
#pragma unroll
  for (int i = 0; i < 4; ++i)
#pragma unroll
    for (int j = 0; j < 4; ++j) acc[i][j] = (f32x4)0.f;

  const size_t Astep = (size_t)(M >> 4) * 1024;
  const size_t Bstep = (size_t)(N >> 4) * 1024;
  const char* Ag = (const char*)Apk + (size_t)kt0 * Astep +
                   (size_t)(blockIdx.y * 8) * 1024 + lane * 16;
  const char* Bg = (const char*)Bpk + (size_t)kt0 * Bstep +
                   (size_t)(blockIdx.x * 8) * 1024 + lane * 16;

  // staging: 16 units (A:8 + B:8) / 4 waves = 4 per wave
  auto stage = [&](int k, int s) {
    const int u = wv * 4 + s;
    char* dst = (char*)SM + (k & 3) * 16384 +
                (u < 8 ? u * 1024 : 8192 + (u - 8) * 1024);
    const char* src = (u < 8) ? Ag + (size_t)k * Astep + u * 1024
                              : Bg + (size_t)k * Bstep + (u - 8) * 1024;
    gl2lds16(src, dst);
  };

#pragma unroll
  for (int k = 0; k < 3; ++k)
#pragma unroll
    for (int s = 0; s < 4; ++s) stage(k, s);
  asm volatile("s_waitcnt vmcnt(8)" ::: "memory");
  __builtin_amdgcn_s_barrier();
  __builtin_amdgcn_sched_barrier(0);

  for (int t = 0; t < nkt; ++t) {
    const _Float16* As = SM + (t & 3) * 8192;
    const _Float16* Bs = As + 4096;
    f16x8 af[4], bf[4];
#pragma unroll
    for (int i = 0; i < 4; ++i)
      af[i] = *(const f16x8*)(As + (wr * 4 + i) * 512 + lane * 8);
#pragma unroll
    for (int j = 0; j < 4; ++j)
      bf[j] = *(const f16x8*)(Bs + (wc * 4 + j) * 512 + lane * 8);
    if (t + 3 < nkt)
#pragma unroll
      for (int s = 0; s < 4; ++s) stage(t + 3, s);
    __builtin_amdgcn_s_setprio(1);
#pragma unroll
    for (int i = 0; i < 4; ++i)
#pragma unroll
      for (int j = 0; j < 4; ++j)
        acc[i][j] = __builtin_amdgcn_mfma_f32_16x16x32_f16(af[i], bf[j], acc[i][j], 0, 0, 0);
    __builtin_amdgcn_s_setprio(0);
    if (t < nkt - 3)       asm volatile("s_waitcnt vmcnt(8)" ::: "memory");
    else if (t == nkt - 3) asm volatile("s_waitcnt vmcnt(4)" ::: "memory");
    else if (t == nkt - 2) asm volatile("s_waitcnt vmcnt(0)" ::: "memory");
    __builtin_amdgcn_s_barrier();
    __builtin_amdgcn_sched_barrier(0);
  }

  // C write: identical layout to validated R4-R6 gemm_f16 epilogue
  const int row0 = blockIdx.y * 128 + wr * 64 + ((lane >> 4) << 2);
  const int col0 = blockIdx.x * 128 + wc * 64 + (lane & 15);
#pragma unroll
  for (int i = 0; i < 4; ++i)
#pragma unroll
    for (int j = 0; j < 4; ++j) {
#pragma unroll
      for (int r = 0; r < 4; ++r)
        C[(size_t)(row0 + i * 16 + r) * N + col0 + j * 16] = acc[i][j][r];
    }
}

__global__ __launch_bounds__(256)
void reduce_add(const float4* __restrict__ a, const float4* __restrict__ b,
                float4* __restrict__ o, int n4) {
  for (int i = blockIdx.x * 256 + threadIdx.x; i < n4; i += gridDim.x * 256) {
    const float4 x = a[i], y = b[i];
    o[i] = make_float4(x.x + y.x, x.y + y.y, x.z + y.z, x.w + y.w);
  }
}

// ---------------------------------------------------------------------------
// MFMA flash attention (R13, validated): staged K/V with pipelined staging.
// K single-buf + V double-buf; stage kt+64 issued at the post-QK barrier,
// drained by vmcnt(0) AFTER softmax+PV.
// ---------------------------------------------------------------------------
__global__ __launch_bounds__(256)
void attn_mfma(const _Float16* __restrict__ Qpk, const _Float16* __restrict__ Kpk,
               const _Float16* __restrict__ Vpk, _Float16* __restrict__ Ap2) {
  const int h = blockIdx.x;
  const int q0 = blockIdx.y * 128;
  const int kvh = h >> 3;
  const int tid = threadIdx.x;
  const int lane = tid & 63;
  const int wv = tid >> 6;
  const int l15 = lane & 15;
  const int l4 = lane >> 4;

  __shared__ _Float16 SM[8192 + 2 * 8192 + 4 * 32 * PSTR];
  _Float16* Ks = SM;
  _Float16* Vs = SM + 8192;            // two 8192-f16 buffers
  _Float16* Pw = SM + 24576 + wv * 32 * PSTR;

  f16x8 qfA[4], qfB[4];
  {
    const _Float16* qa = Qpk + ((size_t)h * 128 + (q0 >> 4) + wv * 2) * 2048 + lane * 8;
#pragma unroll
    for (int ds = 0; ds < 4; ++ds) {
      qfA[ds] = *(const f16x8*)(qa + ds * 512);
      qfB[ds] = *(const f16x8*)(qa + 2048 + ds * 512);
    }
  }

  f16x8 ones;
#pragma unroll
  for (int j = 0; j < 8; ++j) ones[j] = (_Float16)1.0f;

  f32x4 OA[8], OB[8];
#pragma unroll
  for (int dt = 0; dt < 8; ++dt) { OA[dt] = (f32x4)0.f; OB[dt] = (f32x4)0.f; }
  f32x4 LA = (f32x4)0.f, LB = (f32x4)0.f;

  int kstart = q0 - (WINDOW - 1);
  if (kstart < 0) kstart = 0;
  kstart &= ~63;
  const int kend = q0 + 128;

  // stage K[kt2] -> Ks, V[kt2] -> Vs[vb]  (8 gl2lds per wave)
  auto stageKV = [&](int kt2, int vb) {
    const _Float16* Kg = Kpk + ((size_t)kvh * 128 + (kt2 >> 4)) * 2048 + lane * 8;
    const _Float16* Vg = Vpk + ((size_t)kvh * 32 + (kt2 >> 6)) * 8192 + lane * 8;
#pragma unroll
    for (int t = wv; t < 16; t += 4) {
      gl2lds16(Kg + t * 512, (char*)Ks + t * 1024);
      gl2lds16(Vg + t * 512, (char*)(Vs + vb * 8192) + t * 1024);
    }
  };

  // prologue: stage first tile, drain, barrier
  stageKV(kstart, 0);
  asm volatile("s_waitcnt vmcnt(0)" ::: "memory");
  __builtin_amdgcn_s_barrier();
  __builtin_amdgcn_sched_barrier(0);

  int vbuf = 0;
  for (int kt = kstart; kt < kend; kt += 64) {
    // ---- QK^T from Ks ----
    f32x4 sA[4], sB[4];
#pragma unroll
    for (int nt = 0; nt < 4; ++nt) { sA[nt] = (f32x4)(-MLOG2E); sB[nt] = (f32x4)(-MLOG2E); }
    __builtin_amdgcn_s_setprio(1);
#pragma unroll
    for (int ds = 0; ds < 4; ++ds) {
#pragma unroll
      for (int nt = 0; nt < 4; ++nt) {
        const f16x8 kf = *(const f16x8*)(Ks + (nt * 4 + ds) * 512 + lane * 8);
        sA[nt] = __builtin_amdgcn_mfma_f32_16x16x32_f16(qfA[ds], kf, sA[nt], 0, 0, 0);
        sB[nt] = __builtin_amdgcn_mfma_f32_16x16x32_f16(qfB[ds], kf, sB[nt], 0, 0, 0);
      }
    }
    __builtin_amdgcn_s_setprio(0);
    // all waves done reading Ks -> safe to overwrite; V[kt] still live in Vs[vbuf]
    __builtin_amdgcn_s_barrier();
    __builtin_amdgcn_sched_barrier(0);
    if (kt + 64 < kend) stageKV(kt + 64, vbuf ^ 1);

    // ---- softmax -> Pw (wave-private) ----
    const int qbA = q0 + wv * 32 + l4 * 4;
    const int kb = kt + l15;
#pragma unroll
    for (int nt = 0; nt < 4; ++nt) {
      const int kidx = kb + nt * 16;
#pragma unroll
      for (int r = 0; r < 4; ++r) {
        float pA = __builtin_amdgcn_exp2f(sA[nt][r]);
        float pB = __builtin_amdgcn_exp2f(sB[nt][r]);
        pA = ((unsigned)(qbA + r - kidx) < WINDOW) ? pA : 0.f;
        pB = ((unsigned)(qbA + 16 + r - kidx) < WINDOW) ? pB : 0.f;
        Pw[(l4 * 4 + r) * PSTR + nt * 16 + l15] = (_Float16)pA;
        Pw[(16 + l4 * 4 + r) * PSTR + nt * 16 + l15] = (_Float16)pB;
      }
    }

    // ---- P @ V from Vs[vbuf] ----
    const _Float16* Vcur = Vs + vbuf * 8192;
    __builtin_amdgcn_s_setprio(1);
#pragma unroll
    for (int ks = 0; ks < 2; ++ks) {
      const f16x8 pfA = *(const f16x8*)(Pw + l15 * PSTR + ks * 32 + l4 * 8);
      const f16x8 pfB = *(const f16x8*)(Pw + (16 + l15) * PSTR + ks * 32 + l4 * 8);
      LA = __builtin_amdgcn_mfma_f32_16x16x32_f16(pfA, ones, LA, 0, 0, 0);
      LB = __builtin_amdgcn_mfma_f32_16x16x32_f16(pfB, ones, LB, 0, 0, 0);
#pragma unroll
      for (int dt = 0; dt < 8; ++dt) {
        const f16x8 vf = *(const f16x8*)(Vcur + (ks * 8 + dt) * 512 + lane * 8);
        OA[dt] = __builtin_amdgcn_mfma_f32_16x16x32_f16(pfA, vf, OA[dt], 0, 0, 0);
        OB[dt] = __builtin_amdgcn_mfma_f32_16x16x32_f16(pfB, vf, OB[dt], 0, 0, 0);
      }
    }
    __builtin_amdgcn_s_setprio(0);
    // drain this iteration's staging (covered by softmax+PV above), fence
    asm volatile("s_waitcnt vmcnt(0)" ::: "memory");
    __builtin_amdgcn_s_barrier();
    __builtin_amdgcn_sched_barrier(0);
    vbuf ^= 1;
  }

  // epilogue: Tw aliases SM[0..8704) (Ks/Vs dead; all waves past final barrier)
  _Float16* Tw = SM + wv * 16 * ESTR;
#pragma unroll
  for (int half = 0; half < 2; ++half) {
    const f32x4* O = half ? OB : OA;
    const f32x4  L = half ? LB : LA;
    float inv[4];
#pragma unroll
    for (int r = 0; r < 4; ++r) inv[r] = 1.0f / L[r];
#pragma unroll
    for (int dt = 0; dt < 8; ++dt)
#pragma unroll
      for (int r = 0; r < 4; ++r)
        Tw[(l4 * 4 + r) * ESTR + dt * 16 + l15] = (_Float16)(O[dt][r] * inv[r]);
    const int qt = (q0 >> 4) + wv * 2 + half;
#pragma unroll
    for (int ds = 0; ds < 4; ++ds) {
      const f16x8 frag = *(const f16x8*)(Tw + l15 * ESTR + ds * 32 + l4 * 8);
      *(f16x8*)(Ap2 + ((size_t)(h * 4 + ds) * 128 + qt) * 512 + lane * 8) = frag;
    }
  }
}

// ---------------------------------------------------------------------------
// Launch (5 dispatches)
// ---------------------------------------------------------------------------
extern "C" void kernel_launch(void* const* d_in, const int* in_sizes, int n_in,
                              void* d_out, int out_size, void* d_ws, size_t ws_size,
                              hipStream_t stream) {
  const int*   positions = (const int*)d_in[0];
  const float* hidden    = (const float*)d_in[1];
  const float* w_qkv     = (const float*)d_in[2];
  const float* w_o       = (const float*)d_in[3];
  const float* q_norm_w  = (const float*)d_in[4];
  const float* k_norm_w  = (const float*)d_in[5];
  float* out = (float*)d_out;

  // workspace (same 139.5 MB footprint as R6)
  char* ws = (char*)d_ws;
  _Float16* Kpk = (_Float16*)ws;                    // 2.1 MB
  _Float16* Vpk = Kpk + (size_t)T * NKV * D;        // 2.1 MB
  ws += (size_t)T * QKVW * 4;
  _Float16* Ap2 = (_Float16*)ws;                    // 16.8 MB
  float* P0 = (float*)(ws + (size_t)T * ODIM * 2);  // 16.8 MB
  ws += (size_t)T * ODIM * 4;
  float* cosT = (float*)ws;  ws += (size_t)T * 64 * 4;
  float* sinT = (float*)ws;  ws += (size_t)T * 64 * 4;
  _Float16* Bp1 = (_Float16*)ws; ws += (size_t)HIDDEN * QKVW * 2;  // 21.0 MB
  _Float16* Bp2 = (_Float16*)ws; ws += (size_t)ODIM * HIDDEN * 2;  // 16.8 MB
  _Float16* Ah1 = (_Float16*)ws; ws += (size_t)T * HIDDEN * 2;     // 8.4 MB
  _Float16* Qpk = (_Float16*)ws;                    // dead after attn
  float* P1 = (float*)Qpk;                          // alias: written after attn
  ws += (size_t)T * ODIM * 2;

  // 0) all packing + RoPE tables in one dispatch
  prep<<<dim3(NB_A + NB_B1 + NB_B2 + T / 64), 256, 0, stream>>>(
      hidden, w_qkv, w_o, positions, Ah1, Bp1, Bp2, cosT, sinT);

  // 1) fused qkv GEMM + RMSNorm/RoPE/pack (ring-3, 48KB, 3 blocks/CU)
  gemm_qkv<<<dim3(QKVW / 128, T / 128), 256, 49152, stream>>>(
      Ah1, Bp1, q_norm_w, k_norm_w, cosT, sinT, Qpk, Kpk, Vpk);

  // 2) MFMA flash attention (pipelined staged K/V) -> Ap2
  attn_mfma<<<dim3(NH, T / 128), 256, 0, stream>>>(Qpk, Kpk, Vpk, Ap2);

  // 3) out = attn @ w_o, split-K=2 (ring-4, 512 blocks = 2/CU exact)
  gemm_f16p<<<dim3(HIDDEN / 128, T / 128, 2), 256, 65536, stream>>>(
      Ap2, Bp2, P0, P1, T, HIDDEN, ODIM / 32 / 2);
  reduce_add<<<dim3(1024), 256, 0, stream>>>((const float4*)P0, (const float4*)P1,
                                             (float4*)out, T * HIDDEN / 4);
}

// Round 15
// 283.443 us; speedup vs baseline: 1.0022x; 1.0022x over previous
//
#include <hip/hip_runtime.h>
#include <math.h>

// Problem constants
#define T      2048
#define HIDDEN 2048
#define NH     32
#define NKV    4
#define D      128
#define WINDOW 512
#define QKVW   ((NH + 2 * NKV) * D)   // 5120
#define ODIM   (NH * D)               // 4096
#define EPS    1e-6f
#define SCALE  0.08838834764831845f   // D^-0.5
#define PSTR   68                     // attn P-slab stride (validated R5)
#define ESTR   136                    // Q/K epilogue slab stride (16B-aligned rows)
#define VSTR   36                     // V epilogue slab stride (8B-aligned)
#define QMUL   ((float)(0.08838834764831845 * 1.4426950408889634))
#define MLOG2E 5.7707801635558536f    // 4.0*log2(e); |score|<=11.3 (Cauchy-Schwarz)

typedef _Float16 f16x8 __attribute__((ext_vector_type(8)));
typedef _Float16 f16x4 __attribute__((ext_vector_type(4)));
typedef float    f32x4 __attribute__((ext_vector_type(4)));

// ---------------------------------------------------------------------------
// Packed fragment format (validated R2-R6):
// chunk c = q*16 + o (q=c>>4, o=c&15), chunk = 8 k-consecutive f16 at outer o.
// A-operand: lane holds A[m=lane&15][k=(lane>>4)*8+j]
// B-operand: lane holds B[k=(lane>>4)*8+j][n=lane&15]
// ---------------------------------------------------------------------------

__device__ __forceinline__ void gl2lds16(const void* g, void* l) {
  __builtin_amdgcn_global_load_lds((const __attribute__((address_space(1))) void*)g,
                                   (__attribute__((address_space(3))) void*)l,
                                   16, 0, 0);
}

// ---------------------------------------------------------------------------
// prep: all input packing + RoPE tables in ONE dispatch (block-range branch).
// ---------------------------------------------------------------------------
#define NB_A  2048
#define NB_B1 5120
#define NB_B2 4096
__global__ __launch_bounds__(256)
void prep(const float* __restrict__ hidden, const float* __restrict__ w_qkv,
          const float* __restrict__ w_o, const int* __restrict__ positions,
          _Float16* __restrict__ Ah1, _Float16* __restrict__ Bp1,
          _Float16* __restrict__ Bp2, float* __restrict__ cosT,
          float* __restrict__ sinT) {
  const int bx = blockIdx.x;
  const int tid = threadIdx.x;
  if (bx < NB_A) {
    // pack A: hidden [T][HIDDEN] -> A-frag chunks
    const int cid = bx * 256 + tid;
    const int c = cid & 63;
    const int tile = cid >> 6;
    const int mtg = tile & (T / 16 - 1);
    const int kt = tile >> 7;
    const float* src = hidden + (size_t)(mtg * 16 + (c & 15)) * HIDDEN + kt * 32 + (c >> 4) * 8;
    const float4 a = *(const float4*)src;
    const float4 b = *(const float4*)(src + 4);
    f16x8 h;
    h[0] = (_Float16)a.x; h[1] = (_Float16)a.y; h[2] = (_Float16)a.z; h[3] = (_Float16)a.w;
    h[4] = (_Float16)b.x; h[5] = (_Float16)b.y; h[6] = (_Float16)b.z; h[7] = (_Float16)b.w;
    *(f16x8*)(Ah1 + (size_t)cid * 8) = h;
  } else if (bx < NB_A + NB_B1) {
    // pack B: w_qkv [HIDDEN][QKVW]
    const int cid = (bx - NB_A) * 256 + tid;
    const int c = cid & 63;
    const int tile = cid >> 6;
    const int ntg = tile % (QKVW >> 4);
    const int kt = tile / (QKVW >> 4);
    const float* src = w_qkv + (size_t)(kt * 32 + (c >> 4) * 8) * QKVW + ntg * 16 + (c & 15);
    f16x8 h;
#pragma unroll
    for (int j = 0; j < 8; ++j) h[j] = (_Float16)src[(size_t)j * QKVW];
    *(f16x8*)(Bp1 + (size_t)cid * 8) = h;
  } else if (bx < NB_A + NB_B1 + NB_B2) {
    // pack B: w_o [ODIM][HIDDEN]
    const int cid = (bx - NB_A - NB_B1) * 256 + tid;
    const int c = cid & 63;
    const int tile = cid >> 6;
    const int ntg = tile & (HIDDEN / 16 - 1);
    const int kt = tile >> 7;
    const float* src = w_o + (size_t)(kt * 32 + (c >> 4) * 8) * HIDDEN + ntg * 16 + (c & 15);
    f16x8 h;
#pragma unroll
    for (int j = 0; j < 8; ++j) h[j] = (_Float16)src[(size_t)j * HIDDEN];
    *(f16x8*)(Bp2 + (size_t)cid * 8) = h;
  } else {
    // RoPE tables: 64 positions per block
    const int p0 = (bx - NB_A - NB_B1 - NB_B2) * 64 + (tid >> 6) * 16;
    const int j = tid & 63;
    const float invf = (float)pow(1.0e6, -(double)j / 64.0);
#pragma unroll 4
    for (int i = 0; i < 16; ++i) {
      const int t = p0 + i;
      const float ang = (float)positions[t] * invf;
      cosT[t * 64 + j] = cosf(ang);
      sinT[t * 64 + j] = sinf(ang);
    }
  }
}

// ---------------------------------------------------------------------------
// gemm1 fused (R16): R12-validated ring-3 + bijective XCD-chunked swizzle.
// nwg=640=8x80: swz=(bid&7)*80+(bid>>3) gives each XCD 2 full by-rows ->
// each A-panel lives in exactly ONE XCD L2 (was 8x duplicated; FETCH 49.7MB
// vs 29.4 compulsory). Latency-bound so expect modest dur gain, big FETCH cut.
// ---------------------------------------------------------------------------
#define KSTEPS 64   // HIDDEN / 32

__global__ __launch_bounds__(256, 3)
void gemm_qkv(const _Float16* __restrict__ Apk, const _Float16* __restrict__ Bpk,
              const float* __restrict__ qnw, const float* __restrict__ knw,
              const float* __restrict__ cosT, const float* __restrict__ sinT,
              _Float16* __restrict__ Qpk, _Float16* __restrict__ Kpk,
              _Float16* __restrict__ Vpk) {
  extern __shared__ _Float16 SM[];
  const int tid = threadIdx.x;
  const int lane = tid & 63;
  const int wv = tid >> 6;       // 0..3; wave owns rows wv*32..+32
  const int l15 = lane & 15;
  const int l4 = lane >> 4;
  // XCD-chunked bijective swizzle (640 = 8 x 80)
  const int bid = blockIdx.y * 40 + blockIdx.x;
  const int swz = (bid & 7) * 80 + (bid >> 3);
  const int bx = swz % 40, by = swz / 40;

  f32x4 acc[2][8];
#pragma unroll
  for (int i = 0; i < 2; ++i)
#pragma unroll
    for (int j = 0; j < 8; ++j) acc[i][j] = (f32x4)0.f;

  // staging: 16 units (A:8 row-tiles + B:8 col-tiles) / 4 waves = 4 per wave
  auto stage = [&](int k, int s) {
    const int u = wv * 4 + s;
    char* dst = (char*)SM + (k % 3) * 16384 +
                (u < 8 ? u * 1024 : 8192 + (u - 8) * 1024);
    const char* src = (u < 8)
        ? (const char*)Apk + ((size_t)k * (T / 16) + by * 8 + u) * 1024 + lane * 16
        : (const char*)Bpk + ((size_t)k * (QKVW / 16) + bx * 8 + (u - 8)) * 1024 + lane * 16;
    gl2lds16(src, dst);
  };

  // prologue: stage k = 0,1 ; wait for k=0 (4 younger stay in flight)
#pragma unroll
  for (int k = 0; k < 2; ++k)
#pragma unroll
    for (int s = 0; s < 4; ++s) stage(k, s);
  asm volatile("s_waitcnt vmcnt(4)" ::: "memory");
  __builtin_amdgcn_s_barrier();
  __builtin_amdgcn_sched_barrier(0);

  int slot = 0;
  for (int t = 0; t < KSTEPS; ++t) {
    const _Float16* As = SM + slot * 8192;
    const _Float16* Bs = As + 4096;
    f16x8 af[2], bf[8];
#pragma unroll
    for (int i = 0; i < 2; ++i)
      af[i] = *(const f16x8*)(As + (wv * 2 + i) * 512 + lane * 8);
#pragma unroll
    for (int j = 0; j < 8; ++j)
      bf[j] = *(const f16x8*)(Bs + j * 512 + lane * 8);
    // prefetch k = t+2 into the slot freed at the end of step t-1
    if (t + 2 < KSTEPS)
#pragma unroll
      for (int s = 0; s < 4; ++s) stage(t + 2, s);
    __builtin_amdgcn_s_setprio(1);
#pragma unroll
    for (int i = 0; i < 2; ++i)
#pragma unroll
      for (int j = 0; j < 8; ++j)
        acc[i][j] = __builtin_amdgcn_mfma_f32_16x16x32_f16(af[i], bf[j], acc[i][j], 0, 0, 0);
    __builtin_amdgcn_s_setprio(0);
    // boundary: counted wait -> next step's slot fully staged
    if (t < KSTEPS - 2)       asm volatile("s_waitcnt vmcnt(4)" ::: "memory");
    else if (t == KSTEPS - 2) asm volatile("s_waitcnt vmcnt(0)" ::: "memory");
    __builtin_amdgcn_s_barrier();
    __builtin_amdgcn_sched_barrier(0);
    slot = (slot == 2) ? 0 : slot + 1;
  }
  __syncthreads();   // fence staging before epilogue slab reuse

  // ---- fused epilogue (validated R2-R6, byte-identical indexing) ----
  if (bx < NH + NKV) {
    const bool isq = bx < NH;
    const float* w = isq ? qnw : knw;
    const float omul = isq ? QMUL : 1.0f;
    float wcol[8];
#pragma unroll
    for (int j = 0; j < 8; ++j) wcol[j] = w[j * 16 + l15];

    _Float16* ex = SM + wv * (32 * ESTR);   // wave-private 32 x 136
#pragma unroll
    for (int i = 0; i < 2; ++i)
#pragma unroll
      for (int r = 0; r < 4; ++r) {
        float ss = 0.f;
#pragma unroll
        for (int j = 0; j < 8; ++j) ss += acc[i][j][r] * acc[i][j][r];
        ss += __shfl_xor(ss, 1); ss += __shfl_xor(ss, 2);
        ss += __shfl_xor(ss, 4); ss += __shfl_xor(ss, 8);
        const float rn = 1.0f / sqrtf(ss * (1.0f / D) + EPS);
        const int row = i * 16 + l4 * 4 + r;
        const int t = by * 128 + wv * 32 + row;
#pragma unroll
        for (int j = 0; j < 4; ++j) {
          const int jc = j * 16 + l15;
          const float c = cosT[t * 64 + jc];
          const float s = sinT[t * 64 + jc];
          const float x1 = acc[i][j][r] * rn * wcol[j];
          const float x2 = acc[i][j + 4][r] * rn * wcol[j + 4];
          ex[row * ESTR + jc]      = (_Float16)((x1 * c - x2 * s) * omul);
          ex[row * ESTR + 64 + jc] = (_Float16)((x2 * c + x1 * s) * omul);
        }
      }
    // read back in A-frag order (in-wave lgkmcnt ordering, no barrier)
    const int hl = isq ? bx : bx - NH;
    _Float16* dst0 = isq ? Qpk : Kpk;
#pragma unroll
    for (int u = 0; u < 2; ++u) {
      const int qt = by * 8 + wv * 2 + u;
#pragma unroll
      for (int ds = 0; ds < 4; ++ds) {
        const f16x8 frag = *(const f16x8*)(ex + (u * 16 + l15) * ESTR + ds * 32 + l4 * 8);
        *(f16x8*)(dst0 + ((size_t)(hl * 128 + qt) * 4 + ds) * 512 + lane * 8) = frag;
      }
    }
  } else {
    // V: cast + transpose to validated Vpk B-operand layout, wave-private
    const int kvh = bx - NH - NKV;
    _Float16* exv = SM + wv * (128 * VSTR);  // [d 0..127][local key 0..31]
#pragma unroll
    for (int i = 0; i < 2; ++i)
#pragma unroll
      for (int j = 0; j < 8; ++j) {
        f16x4 v4;
#pragma unroll
        for (int r = 0; r < 4; ++r) v4[r] = (_Float16)acc[i][j][r];
        *(f16x4*)(exv + (j * 16 + l15) * VSTR + i * 16 + l4 * 4) = v4;
      }
    const int kt64 = by * 2 + (wv >> 1);
    const int ks = wv & 1;
#pragma unroll
    for (int dt = 0; dt < 8; ++dt) {
      const f16x4 lo = *(const f16x4*)(exv + (dt * 16 + l15) * VSTR + l4 * 8);
      const f16x4 hi = *(const f16x4*)(exv + (dt * 16 + l15) * VSTR + l4 * 8 + 4);
      f16x8 h8;
#pragma unroll
      for (int r = 0; r < 4; ++r) { h8[r] = lo[r]; h8[r + 4] = hi[r]; }
      *(f16x8*)(Vpk + (((size_t)(kvh * 32 + kt64) * 2 + ks) * 8 + dt) * 512 + lane * 8) = h8;
    }
  }
}

// ---------------------------------------------------------------------------
// gemm2 (R16): R11/R12-validated RING-3 (ring-4's inferred win was cross-run
// noise; this round is the A/B) + bijective XCD swizzle (512 = 8 x 64; each
// XCD gets 4 by-rows of one split -> A-panels pinned, z-splits on disjoint
// XCD halves).
// ---------------------------------------------------------------------------
__global__ __launch_bounds__(256, 3)
void gemm_f16p(const _Float16* __restrict__ Apk, const _Float16* __restrict__ Bpk,
               float* __restrict__ C0, float* __restrict__ C1,
               int M, int N, int nkt) {
  extern __shared__ _Float16 SM[];
  const int tid = threadIdx.x;
  const int lane = tid & 63;
  const int wv = tid >> 6;
  const int wr = wv & 1, wc = wv >> 1;
  // XCD-chunked bijective swizzle (512 = 8 x 64)
  const int bid = blockIdx.x + blockIdx.y * 16 + blockIdx.z * 256;
  const int swz = (bid & 7) * 64 + (bid >> 3);
  const int sbx = swz & 15, sby = (swz >> 4) & 15, kz = swz >> 8;
  const int kt0 = kz * nkt;
  float* __restrict__ C = kz ? C1 : C0;

  f32x4 acc[4][4];
#pragma unroll
  for (int i = 0; i < 4; ++i)
#pragma unroll
    for (int j = 0; j < 4; ++j) acc[i][j] = (f32x4)0.f;

  const size_t Astep = (size_t)(M >> 4) * 1024;
  const size_t Bstep = (size_t)(N >> 4) * 1024;
  const char* Ag = (const char*)Apk + (size_t)kt0 * Astep +
                   (size_t)(sby * 8) * 1024 + lane * 16;
  const char* Bg = (const char*)Bpk + (size_t)kt0 * Bstep +
                   (size_t)(sbx * 8) * 1024 + lane * 16;

  // staging: 16 units (A:8 + B:8) / 4 waves = 4 per wave
  auto stage = [&](int k, int s) {
    const int u = wv * 4 + s;
    char* dst = (char*)SM + (k % 3) * 16384 +
                (u < 8 ? u * 1024 : 8192 + (u - 8) * 1024);
    const char* src = (u < 8) ? Ag + (size_t)k * Astep + u * 1024
                              : Bg + (size_t)k * Bstep + (u - 8) * 1024;
    gl2lds16(src, dst);
  };

#pragma unroll
  for (int k = 0; k < 2; ++k)
#pragma unroll
    for (int s = 0; s < 4; ++s) stage(k, s);
  asm volatile("s_waitcnt vmcnt(4)" ::: "memory");
  __builtin_amdgcn_s_barrier();
  __builtin_amdgcn_sched_barrier(0);

  int slot = 0;
  for (int t = 0; t < nkt; ++t) {
    const _Float16* As = SM + slot * 8192;
    const _Float16* Bs = As + 4096;
    f16x8 af[4], bf[4];
#pragma unroll
    for (int i = 0; i < 4; ++i)
      af[i] = *(const f16x8*)(As + (wr * 4 + i) * 512 + lane * 8);
#pragma unroll
    for (int j = 0; j < 4; ++j)
      bf[j] = *(const f16x8*)(Bs + (wc * 4 + j) * 512 + lane * 8);
    if (t + 2 < nkt)
#pragma unroll
      for (int s = 0; s < 4; ++s) stage(t + 2, s);
    __builtin_amdgcn_s_setprio(1);
#pragma unroll
    for (int i = 0; i < 4; ++i)
#pragma unroll
      for (int j = 0; j < 4; ++j)
        acc[i][j] = __builtin_amdgcn_mfma_f32_16x16x32_f16(af[i], bf[j], acc[i][j], 0, 0, 0);
    __builtin_amdgcn_s_setprio(0);
    if (t < nkt - 2)       asm volatile("s_waitcnt vmcnt(4)" ::: "memory");
    else if (t == nkt - 2) asm volatile("s_waitcnt vmcnt(0)" ::: "memory");
    __builtin_amdgcn_s_barrier();
    __builtin_amdgcn_sched_barrier(0);
    slot = (slot == 2) ? 0 : slot + 1;
  }

  // C write: identical layout to validated R4-R6 gemm_f16 epilogue
  const int row0 = sby * 128 + wr * 64 + ((lane >> 4) << 2);
  const int col0 = sbx * 128 + wc * 64 + (lane & 15);
#pragma unroll
  for (int i = 0; i < 4; ++i)
#pragma unroll
    for (int j = 0; j < 4; ++j) {
#pragma unroll
      for (int r = 0; r < 4; ++r)
        C[(size_t)(row0 + i * 16 + r) * N + col0 + j * 16] = acc[i][j][r];
    }
}

__global__ __launch_bounds__(256)
void reduce_add(const float4* __restrict__ a, const float4* __restrict__ b,
                float4* __restrict__ o, int n4) {
  for (int i = blockIdx.x * 256 + threadIdx.x; i < n4; i += gridDim.x * 256) {
    const float4 x = a[i], y = b[i];
    o[i] = make_float4(x.x + y.x, x.y + y.y, x.z + y.z, x.w + y.w);
  }
}

// ---------------------------------------------------------------------------
// MFMA flash attention (R13, validated): staged K/V with pipelined staging.
// K single-buf + V double-buf; stage kt+64 issued at the post-QK barrier,
// drained by vmcnt(0) AFTER softmax+PV.
// ---------------------------------------------------------------------------
__global__ __launch_bounds__(256)
void attn_mfma(const _Float16* __restrict__ Qpk, const _Float16* __restrict__ Kpk,
               const _Float16* __restrict__ Vpk, _Float16* __restrict__ Ap2) {
  const int h = blockIdx.x;
  const int q0 = blockIdx.y * 128;
  const int kvh = h >> 3;
  const int tid = threadIdx.x;
  const int lane = tid & 63;
  const int wv = tid >> 6;
  const int l15 = lane & 15;
  const int l4 = lane >> 4;

  __shared__ _Float16 SM[8192 + 2 * 8192 + 4 * 32 * PSTR];
  _Float16* Ks = SM;
  _Float16* Vs = SM + 8192;            // two 8192-f16 buffers
  _Float16* Pw = SM + 24576 + wv * 32 * PSTR;

  f16x8 qfA[4], qfB[4];
  {
    const _Float16* qa = Qpk + ((size_t)h * 128 + (q0 >> 4) + wv * 2) * 2048 + lane * 8;
#pragma unroll
    for (int ds = 0; ds < 4; ++ds) {
      qfA[ds] = *(const f16x8*)(qa + ds * 512);
      qfB[ds] = *(const f16x8*)(qa + 2048 + ds * 512);
    }
  }

  f16x8 ones;
#pragma unroll
  for (int j = 0; j < 8; ++j) ones[j] = (_Float16)1.0f;

  f32x4 OA[8], OB[8];
#pragma unroll
  for (int dt = 0; dt < 8; ++dt) { OA[dt] = (f32x4)0.f; OB[dt] = (f32x4)0.f; }
  f32x4 LA = (f32x4)0.f, LB = (f32x4)0.f;

  int kstart = q0 - (WINDOW - 1);
  if (kstart < 0) kstart = 0;
  kstart &= ~63;
  const int kend = q0 + 128;

  // stage K[kt2] -> Ks, V[kt2] -> Vs[vb]  (8 gl2lds per wave)
  auto stageKV = [&](int kt2, int vb) {
    const _Float16* Kg = Kpk + ((size_t)kvh * 128 + (kt2 >> 4)) * 2048 + lane * 8;
    const _Float16* Vg = Vpk + ((size_t)kvh * 32 + (kt2 >> 6)) * 8192 + lane * 8;
#pragma unroll
    for (int t = wv; t < 16; t += 4) {
      gl2lds16(Kg + t * 512, (char*)Ks + t * 1024);
      gl2lds16(Vg + t * 512, (char*)(Vs + vb * 8192) + t * 1024);
    }
  };

  // prologue: stage first tile, drain, barrier
  stageKV(kstart, 0);
  asm volatile("s_waitcnt vmcnt(0)" ::: "memory");
  __builtin_amdgcn_s_barrier();
  __builtin_amdgcn_sched_barrier(0);

  int vbuf = 0;
  for (int kt = kstart; kt < kend; kt += 64) {
    // ---- QK^T from Ks ----
    f32x4 sA[4], sB[4];
#pragma unroll
    for (int nt = 0; nt < 4; ++nt) { sA[nt] = (f32x4)(-MLOG2E); sB[nt] = (f32x4)(-MLOG2E); }
    __builtin_amdgcn_s_setprio(1);
#pragma unroll
    for (int ds = 0; ds < 4; ++ds) {
#pragma unroll
      for (int nt = 0; nt < 4; ++nt) {
        const f16x8 kf = *(const f16x8*)(Ks + (nt * 4 + ds) * 512 + lane * 8);
        sA[nt] = __builtin_amdgcn_mfma_f32_16x16x32_f16(qfA[ds], kf, sA[nt], 0, 0, 0);
        sB[nt] = __builtin_amdgcn_mfma_f32_16x16x32_f16(qfB[ds], kf, sB[nt], 0, 0, 0);
      }
    }
    __builtin_amdgcn_s_setprio(0);
    // all waves done reading Ks -> safe to overwrite; V[kt] still live in Vs[vbuf]
    __builtin_amdgcn_s_barrier();
    __builtin_amdgcn_sched_barrier(0);
    if (kt + 64 < kend) stageKV(kt + 64, vbuf ^ 1);

    // ---- softmax -> Pw (wave-private) ----
    const int qbA = q0 + wv * 32 + l4 * 4;
    const int kb = kt + l15;
#pragma unroll
    for (int nt = 0; nt < 4; ++nt) {
      const int kidx = kb + nt * 16;
#pragma unroll
      for (int r = 0; r < 4; ++r) {
        float pA = __builtin_amdgcn_exp2f(sA[nt][r]);
        float pB = __builtin_amdgcn_exp2f(sB[nt][r]);
        pA = ((unsigned)(qbA + r - kidx) < WINDOW) ? pA : 0.f;
        pB = ((unsigned)(qbA + 16 + r - kidx) < WINDOW) ? pB : 0.f;
        Pw[(l4 * 4 + r) * PSTR + nt * 16 + l15] = (_Float16)pA;
        Pw[(16 + l4 * 4 + r) * PSTR + nt * 16 + l15] = (_Float16)pB;
      }
    }

    // ---- P @ V from Vs[vbuf] ----
    const _Float16* Vcur = Vs + vbuf * 8192;
    __builtin_amdgcn_s_setprio(1);
#pragma unroll
    for (int ks = 0; ks < 2; ++ks) {
      const f16x8 pfA = *(const f16x8*)(Pw + l15 * PSTR + ks * 32 + l4 * 8);
      const f16x8 pfB = *(const f16x8*)(Pw + (16 + l15) * PSTR + ks * 32 + l4 * 8);
      LA = __builtin_amdgcn_mfma_f32_16x16x32_f16(pfA, ones, LA, 0, 0, 0);
      LB = __builtin_amdgcn_mfma_f32_16x16x32_f16(pfB, ones, LB, 0, 0, 0);
#pragma unroll
      for (int dt = 0; dt < 8; ++dt) {
        const f16x8 vf = *(const f16x8*)(Vcur + (ks * 8 + dt) * 512 + lane * 8);
        OA[dt] = __builtin_amdgcn_mfma_f32_16x16x32_f16(pfA, vf, OA[dt], 0, 0, 0);
        OB[dt] = __builtin_amdgcn_mfma_f32_16x16x32_f16(pfB, vf, OB[dt], 0, 0, 0);
      }
    }
    __builtin_amdgcn_s_setprio(0);
    // drain this iteration's staging (covered by softmax+PV above), fence
    asm volatile("s_waitcnt vmcnt(0)" ::: "memory");
    __builtin_amdgcn_s_barrier();
    __builtin_amdgcn_sched_barrier(0);
    vbuf ^= 1;
  }

  // epilogue: Tw aliases SM[0..8704) (Ks/Vs dead; all waves past final barrier)
  _Float16* Tw = SM + wv * 16 * ESTR;
#pragma unroll
  for (int half = 0; half < 2; ++half) {
    const f32x4* O = half ? OB : OA;
    const f32x4  L = half ? LB : LA;
    float inv[4];
#pragma unroll
    for (int r = 0; r < 4; ++r) inv[r] = 1.0f / L[r];
#pragma unroll
    for (int dt = 0; dt < 8; ++dt)
#pragma unroll
      for (int r = 0; r < 4; ++r)
        Tw[(l4 * 4 + r) * ESTR + dt * 16 + l15] = (_Float16)(O[dt][r] * inv[r]);
    const int qt = (q0 >> 4) + wv * 2 + half;
#pragma unroll
    for (int ds = 0; ds < 4; ++ds) {
      const f16x8 frag = *(const f16x8*)(Tw + l15 * ESTR + ds * 32 + l4 * 8);
      *(f16x8*)(Ap2 + ((size_t)(h * 4 + ds) * 128 + qt) * 512 + lane * 8) = frag;
    }
  }
}

// ---------------------------------------------------------------------------
// Launch (5 dispatches)
// ---------------------------------------------------------------------------
extern "C" void kernel_launch(void* const* d_in, const int* in_sizes, int n_in,
                              void* d_out, int out_size, void* d_ws, size_t ws_size,
                              hipStream_t stream) {
  const int*   positions = (const int*)d_in[0];
  const float* hidden    = (const float*)d_in[1];
  const float* w_qkv     = (const float*)d_in[2];
  const float* w_o       = (const float*)d_in[3];
  const float* q_norm_w  = (const float*)d_in[4];
  const float* k_norm_w  = (const float*)d_in[5];
  float* out = (float*)d_out;

  // workspace (same 139.5 MB footprint as R6)
  char* ws = (char*)d_ws;
  _Float16* Kpk = (_Float16*)ws;                    // 2.1 MB
  _Float16* Vpk = Kpk + (size_t)T * NKV * D;        // 2.1 MB
  ws += (size_t)T * QKVW * 4;
  _Float16* Ap2 = (_Float16*)ws;                    // 16.8 MB
  float* P0 = (float*)(ws + (size_t)T * ODIM * 2);  // 16.8 MB
  ws += (size_t)T * ODIM * 4;
  float* cosT = (float*)ws;  ws += (size_t)T * 64 * 4;
  float* sinT = (float*)ws;  ws += (size_t)T * 64 * 4;
  _Float16* Bp1 = (_Float16*)ws; ws += (size_t)HIDDEN * QKVW * 2;  // 21.0 MB
  _Float16* Bp2 = (_Float16*)ws; ws += (size_t)ODIM * HIDDEN * 2;  // 16.8 MB
  _Float16* Ah1 = (_Float16*)ws; ws += (size_t)T * HIDDEN * 2;     // 8.4 MB
  _Float16* Qpk = (_Float16*)ws;                    // dead after attn
  float* P1 = (float*)Qpk;                          // alias: written after attn
  ws += (size_t)T * ODIM * 2;

  // 0) all packing + RoPE tables in one dispatch
  prep<<<dim3(NB_A + NB_B1 + NB_B2 + T / 64), 256, 0, stream>>>(
      hidden, w_qkv, w_o, positions, Ah1, Bp1, Bp2, cosT, sinT);

  // 1) fused qkv GEMM + RMSNorm/RoPE/pack (ring-3 + XCD swizzle)
  gemm_qkv<<<dim3(QKVW / 128, T / 128), 256, 49152, stream>>>(
      Ah1, Bp1, q_norm_w, k_norm_w, cosT, sinT, Qpk, Kpk, Vpk);

  // 2) MFMA flash attention (pipelined staged K/V) -> Ap2
  attn_mfma<<<dim3(NH, T / 128), 256, 0, stream>>>(Qpk, Kpk, Vpk, Ap2);

  // 3) out = attn @ w_o, split-K=2 (ring-3 + XCD swizzle), then reduce
  gemm_f16p<<<dim3(HIDDEN / 128, T / 128, 2), 256, 49152, stream>>>(
      Ap2, Bp2, P0, P1, T, HIDDEN, ODIM / 32 / 2);
  reduce_add<<<dim3(1024), 256, 0, stream>>>((const float4*)P0, (const float4*)P1,
                                             (float4*)out, T * HIDDEN / 4);
}

// Round 16
// 268.794 us; speedup vs baseline: 1.0569x; 1.0545x over previous
//
#include <hip/hip_runtime.h>
#include <math.h>

// Problem constants
#define T      2048
#define HIDDEN 2048
#define NH     32
#define NKV    4
#define D      128
#define WINDOW 512
#define QKVW   ((NH + 2 * NKV) * D)   // 5120
#define ODIM   (NH * D)               // 4096
#define EPS    1e-6f
#define SCALE  0.08838834764831845f   // D^-0.5
#define PSTR   68                     // attn P-slab stride (validated R5)
#define ESTR   136                    // Q/K epilogue slab stride (16B-aligned rows)
#define VSTR   36                     // V epilogue slab stride (8B-aligned)
#define QMUL   ((float)(0.08838834764831845 * 1.4426950408889634))
#define MLOG2E 5.7707801635558536f    // 4.0*log2(e); |score|<=11.3 (Cauchy-Schwarz)

typedef _Float16 f16x8 __attribute__((ext_vector_type(8)));
typedef _Float16 f16x4 __attribute__((ext_vector_type(4)));
typedef float    f32x4 __attribute__((ext_vector_type(4)));

// ---------------------------------------------------------------------------
// Packed fragment format (validated R2-R6):
// chunk c = q*16 + o (q=c>>4, o=c&15), chunk = 8 k-consecutive f16 at outer o.
// A-operand: lane holds A[m=lane&15][k=(lane>>4)*8+j]
// B-operand: lane holds B[k=(lane>>4)*8+j][n=lane&15]
// ---------------------------------------------------------------------------

__device__ __forceinline__ void gl2lds16(const void* g, void* l) {
  __builtin_amdgcn_global_load_lds((const __attribute__((address_space(1))) void*)g,
                                   (__attribute__((address_space(3))) void*)l,
                                   16, 0, 0);
}

// ---------------------------------------------------------------------------
// prep (R17): B-packs rewritten as LDS-transpose with fully coalesced reads.
// Old form read 8 floats strided by N per thread (~50% line efficiency on
// 75MB of fp32 weights + scalar-load overhead). New: each block packs a
// 32k x 128n region: coalesced f32 reads (wave = 8 rows x 512B contiguous),
// f16 staging in LDS [32][132] (padded stride -> conflict-free columns),
// coalesced 16B chunk writes. Output bytes identical to validated layout.
//   [0, 2048)            pack_a (unchanged)
//   [2048, 4608)         pack_b w_qkv   (64 kt x 40 ng)
//   [4608, 6656)         pack_b w_o     (128 kt x 16 ng)
//   [6656, 6688)         rope tables
// ---------------------------------------------------------------------------
#define NB_A  2048
#define NB_B1 2560
#define NB_B2 2048

__device__ __forceinline__ void pack_b_region(const float* __restrict__ W,
                                              _Float16* __restrict__ Bp,
                                              int N, int kt, int ng, int tid,
                                              _Float16* __restrict__ LS) {
  // read 32 rows x 128 cols coalesced; thread: row r, 16 consecutive floats
  const int r = tid >> 3;
  const int c0 = (tid & 7) * 16;
  const float* src = W + (size_t)(kt * 32 + r) * N + ng * 128 + c0;
#pragma unroll
  for (int v = 0; v < 4; ++v) {
    const float4 f = *(const float4*)(src + v * 4);
    LS[r * 132 + c0 + v * 4 + 0] = (_Float16)f.x;
    LS[r * 132 + c0 + v * 4 + 1] = (_Float16)f.y;
    LS[r * 132 + c0 + v * 4 + 2] = (_Float16)f.z;
    LS[r * 132 + c0 + v * 4 + 3] = (_Float16)f.w;
  }
  __syncthreads();
  // emit 512 chunks (8 tiles x 64); thread writes 2 consecutive chunks
#pragma unroll
  for (int i = 0; i < 2; ++i) {
    const int ch = tid * 2 + i;
    const int tile = ch >> 6;
    const int cc = ch & 63;
    const int q = cc >> 4, o = cc & 15;
    f16x8 v;
#pragma unroll
    for (int j = 0; j < 8; ++j) v[j] = LS[(q * 8 + j) * 132 + tile * 16 + o];
    *(f16x8*)(Bp + ((size_t)(kt * (N / 16) + ng * 8 + tile) * 512) + cc * 8) = v;
  }
}

__global__ __launch_bounds__(256)
void prep(const float* __restrict__ hidden, const float* __restrict__ w_qkv,
          const float* __restrict__ w_o, const int* __restrict__ positions,
          _Float16* __restrict__ Ah1, _Float16* __restrict__ Bp1,
          _Float16* __restrict__ Bp2, float* __restrict__ cosT,
          float* __restrict__ sinT) {
  __shared__ _Float16 LS[32 * 132];
  const int bx = blockIdx.x;
  const int tid = threadIdx.x;
  if (bx < NB_A) {
    // pack A: hidden [T][HIDDEN] -> A-frag chunks (already coalesced)
    const int cid = bx * 256 + tid;
    const int c = cid & 63;
    const int tile = cid >> 6;
    const int mtg = tile & (T / 16 - 1);
    const int kt = tile >> 7;
    const float* src = hidden + (size_t)(mtg * 16 + (c & 15)) * HIDDEN + kt * 32 + (c >> 4) * 8;
    const float4 a = *(const float4*)src;
    const float4 b = *(const float4*)(src + 4);
    f16x8 h;
    h[0] = (_Float16)a.x; h[1] = (_Float16)a.y; h[2] = (_Float16)a.z; h[3] = (_Float16)a.w;
    h[4] = (_Float16)b.x; h[5] = (_Float16)b.y; h[6] = (_Float16)b.z; h[7] = (_Float16)b.w;
    *(f16x8*)(Ah1 + (size_t)cid * 8) = h;
  } else if (bx < NB_A + NB_B1) {
    const int idx = bx - NB_A;
    pack_b_region(w_qkv, Bp1, QKVW, idx / 40, idx % 40, tid, LS);
  } else if (bx < NB_A + NB_B1 + NB_B2) {
    const int idx = bx - NB_A - NB_B1;
    pack_b_region(w_o, Bp2, HIDDEN, idx / 16, idx % 16, tid, LS);
  } else {
    // RoPE tables: 64 positions per block
    const int p0 = (bx - NB_A - NB_B1 - NB_B2) * 64 + (tid >> 6) * 16;
    const int j = tid & 63;
    const float invf = (float)pow(1.0e6, -(double)j / 64.0);
#pragma unroll 4
    for (int i = 0; i < 16; ++i) {
      const int t = p0 + i;
      const float ang = (float)positions[t] * invf;
      cosT[t * 64 + j] = cosf(ang);
      sinT[t * 64 + j] = sinf(ang);
    }
  }
}

// ---------------------------------------------------------------------------
// gemm1 fused (R14-validated 57.3us): 128x128 tile, 4 waves, ring-3
// counted-vmcnt(4), 48KB -> 3 blocks/CU. R15's XCD swizzle REVERTED: it
// doubled FETCH (49.7->107MB, wrong reuse axis) with ZERO dur change ->
// kernel is latency-bound, not BW-bound; swizzle is a non-lever here.
// ---------------------------------------------------------------------------
#define KSTEPS 64   // HIDDEN / 32

__global__ __launch_bounds__(256, 3)
void gemm_qkv(const _Float16* __restrict__ Apk, const _Float16* __restrict__ Bpk,
              const float* __restrict__ qnw, const float* __restrict__ knw,
              const float* __restrict__ cosT, const float* __restrict__ sinT,
              _Float16* __restrict__ Qpk, _Float16* __restrict__ Kpk,
              _Float16* __restrict__ Vpk) {
  extern __shared__ _Float16 SM[];
  const int tid = threadIdx.x;
  const int lane = tid & 63;
  const int wv = tid >> 6;       // 0..3; wave owns rows wv*32..+32
  const int l15 = lane & 15;
  const int l4 = lane >> 4;
  const int bx = blockIdx.x, by = blockIdx.y;

  f32x4 acc[2][8];
#pragma unroll
  for (int i = 0; i < 2; ++i)
#pragma unroll
    for (int j = 0; j < 8; ++j) acc[i][j] = (f32x4)0.f;

  // staging: 16 units (A:8 row-tiles + B:8 col-tiles) / 4 waves = 4 per wave
  auto stage = [&](int k, int s) {
    const int u = wv * 4 + s;
    char* dst = (char*)SM + (k % 3) * 16384 +
                (u < 8 ? u * 1024 : 8192 + (u - 8) * 1024);
    const char* src = (u < 8)
        ? (const char*)Apk + ((size_t)k * (T / 16) + by * 8 + u) * 1024 + lane * 16
        : (const char*)Bpk + ((size_t)k * (QKVW / 16) + bx * 8 + (u - 8)) * 1024 + lane * 16;
    gl2lds16(src, dst);
  };

  // prologue: stage k = 0,1 ; wait for k=0 (4 younger stay in flight)
#pragma unroll
  for (int k = 0; k < 2; ++k)
#pragma unroll
    for (int s = 0; s < 4; ++s) stage(k, s);
  asm volatile("s_waitcnt vmcnt(4)" ::: "memory");
  __builtin_amdgcn_s_barrier();
  __builtin_amdgcn_sched_barrier(0);

  int slot = 0;
  for (int t = 0; t < KSTEPS; ++t) {
    const _Float16* As = SM + slot * 8192;
    const _Float16* Bs = As + 4096;
    f16x8 af[2], bf[8];
#pragma unroll
    for (int i = 0; i < 2; ++i)
      af[i] = *(const f16x8*)(As + (wv * 2 + i) * 512 + lane * 8);
#pragma unroll
    for (int j = 0; j < 8; ++j)
      bf[j] = *(const f16x8*)(Bs + j * 512 + lane * 8);
    // prefetch k = t+2 into the slot freed at the end of step t-1
    if (t + 2 < KSTEPS)
#pragma unroll
      for (int s = 0; s < 4; ++s) stage(t + 2, s);
    __builtin_amdgcn_s_setprio(1);
#pragma unroll
    for (int i = 0; i < 2; ++i)
#pragma unroll
      for (int j = 0; j < 8; ++j)
        acc[i][j] = __builtin_amdgcn_mfma_f32_16x16x32_f16(af[i], bf[j], acc[i][j], 0, 0, 0);
    __builtin_amdgcn_s_setprio(0);
    // boundary: counted wait -> next step's slot fully staged
    if (t < KSTEPS - 2)       asm volatile("s_waitcnt vmcnt(4)" ::: "memory");
    else if (t == KSTEPS - 2) asm volatile("s_waitcnt vmcnt(0)" ::: "memory");
    __builtin_amdgcn_s_barrier();
    __builtin_amdgcn_sched_barrier(0);
    slot = (slot == 2) ? 0 : slot + 1;
  }
  __syncthreads();   // fence staging before epilogue slab reuse

  // ---- fused epilogue (validated R2-R6, byte-identical indexing) ----
  if (bx < NH + NKV) {
    const bool isq = bx < NH;
    const float* w = isq ? qnw : knw;
    const float omul = isq ? QMUL : 1.0f;
    float wcol[8];
#pragma unroll
    for (int j = 0; j < 8; ++j) wcol[j] = w[j * 16 + l15];

    _Float16* ex = SM + wv * (32 * ESTR);   // wave-private 32 x 136
#pragma unroll
    for (int i = 0; i < 2; ++i)
#pragma unroll
      for (int r = 0; r < 4; ++r) {
        float ss = 0.f;
#pragma unroll
        for (int j = 0; j < 8; ++j) ss += acc[i][j][r] * acc[i][j][r];
        ss += __shfl_xor(ss, 1); ss += __shfl_xor(ss, 2);
        ss += __shfl_xor(ss, 4); ss += __shfl_xor(ss, 8);
        const float rn = 1.0f / sqrtf(ss * (1.0f / D) + EPS);
        const int row = i * 16 + l4 * 4 + r;
        const int t = by * 128 + wv * 32 + row;
#pragma unroll
        for (int j = 0; j < 4; ++j) {
          const int jc = j * 16 + l15;
          const float c = cosT[t * 64 + jc];
          const float s = sinT[t * 64 + jc];
          const float x1 = acc[i][j][r] * rn * wcol[j];
          const float x2 = acc[i][j + 4][r] * rn * wcol[j + 4];
          ex[row * ESTR + jc]      = (_Float16)((x1 * c - x2 * s) * omul);
          ex[row * ESTR + 64 + jc] = (_Float16)((x2 * c + x1 * s) * omul);
        }
      }
    // read back in A-frag order (in-wave lgkmcnt ordering, no barrier)
    const int hl = isq ? bx : bx - NH;
    _Float16* dst0 = isq ? Qpk : Kpk;
#pragma unroll
    for (int u = 0; u < 2; ++u) {
      const int qt = by * 8 + wv * 2 + u;
#pragma unroll
      for (int ds = 0; ds < 4; ++ds) {
        const f16x8 frag = *(const f16x8*)(ex + (u * 16 + l15) * ESTR + ds * 32 + l4 * 8);
        *(f16x8*)(dst0 + ((size_t)(hl * 128 + qt) * 4 + ds) * 512 + lane * 8) = frag;
      }
    }
  } else {
    // V: cast + transpose to validated Vpk B-operand layout, wave-private
    const int kvh = bx - NH - NKV;
    _Float16* exv = SM + wv * (128 * VSTR);  // [d 0..127][local key 0..31]
#pragma unroll
    for (int i = 0; i < 2; ++i)
#pragma unroll
      for (int j = 0; j < 8; ++j) {
        f16x4 v4;
#pragma unroll
        for (int r = 0; r < 4; ++r) v4[r] = (_Float16)acc[i][j][r];
        *(f16x4*)(exv + (j * 16 + l15) * VSTR + i * 16 + l4 * 4) = v4;
      }
    const int kt64 = by * 2 + (wv >> 1);
    const int ks = wv & 1;
#pragma unroll
    for (int dt = 0; dt < 8; ++dt) {
      const f16x4 lo = *(const f16x4*)(exv + (dt * 16 + l15) * VSTR + l4 * 8);
      const f16x4 hi = *(const f16x4*)(exv + (dt * 16 + l15) * VSTR + l4 * 8 + 4);
      f16x8 h8;
#pragma unroll
      for (int r = 0; r < 4; ++r) { h8[r] = lo[r]; h8[r + 4] = hi[r]; }
      *(f16x8*)(Vpk + (((size_t)(kvh * 32 + kt64) * 2 + ks) * 8 + dt) * 512 + lane * 8) = h8;
    }
  }
}

// ---------------------------------------------------------------------------
// gemm2 (R11/R12-validated ring-3, swizzle reverted).
// ---------------------------------------------------------------------------
__global__ __launch_bounds__(256, 3)
void gemm_f16p(const _Float16* __restrict__ Apk, const _Float16* __restrict__ Bpk,
               float* __restrict__ C0, float* __restrict__ C1,
               int M, int N, int nkt) {
  extern __shared__ _Float16 SM[];
  const int tid = threadIdx.x;
  const int lane = tid & 63;
  const int wv = tid >> 6;
  const int wr = wv & 1, wc = wv >> 1;
  const int kt0 = blockIdx.z * nkt;
  float* __restrict__ C = blockIdx.z ? C1 : C0;

  f32x4 acc[4][4];
#pragma unroll
  for (int i = 0; i < 4; ++i)
#pragma unroll
    for (int j = 0; j < 4; ++j) acc[i][j] = (f32x4)0.f;

  const size_t Astep = (size_t)(M >> 4) * 1024;
  const size_t Bstep = (size_t)(N >> 4) * 1024;
  const char* Ag = (const char*)Apk + (size_t)kt0 * Astep +
                   (size_t)(blockIdx.y * 8) * 1024 + lane * 16;
  const char* Bg = (const char*)Bpk + (size_t)kt0 * Bstep +
                   (size_t)(blockIdx.x * 8) * 1024 + lane * 16;

  // staging: 16 units (A:8 + B:8) / 4 waves = 4 per wave
  auto stage = [&](int k, int s) {
    const int u = wv * 4 + s;
    char* dst = (char*)SM + (k % 3) * 16384 +
                (u < 8 ? u * 1024 : 8192 + (u - 8) * 1024);
    const char* src = (u < 8) ? Ag + (size_t)k * Astep + u * 1024
                              : Bg + (size_t)k * Bstep + (u - 8) * 1024;
    gl2lds16(src, dst);
  };

#pragma unroll
  for (int k = 0; k < 2; ++k)
#pragma unroll
    for (int s = 0; s < 4; ++s) stage(k, s);
  asm volatile("s_waitcnt vmcnt(4)" ::: "memory");
  __builtin_amdgcn_s_barrier();
  __builtin_amdgcn_sched_barrier(0);

  int slot = 0;
  for (int t = 0; t < nkt; ++t) {
    const _Float16* As = SM + slot * 8192;
    const _Float16* Bs = As + 4096;
    f16x8 af[4], bf[4];
#pragma unroll
    for (int i = 0; i < 4; ++i)
      af[i] = *(const f16x8*)(As + (wr * 4 + i) * 512 + lane * 8);
#pragma unroll
    for (int j = 0; j < 4; ++j)
      bf[j] = *(const f16x8*)(Bs + (wc * 4 + j) * 512 + lane * 8);
    if (t + 2 < nkt)
#pragma unroll
      for (int s = 0; s < 4; ++s) stage(t + 2, s);
    __builtin_amdgcn_s_setprio(1);
#pragma unroll
    for (int i = 0; i < 4; ++i)
#pragma unroll
      for (int j = 0; j < 4; ++j)
        acc[i][j] = __builtin_amdgcn_mfma_f32_16x16x32_f16(af[i], bf[j], acc[i][j], 0, 0, 0);
    __builtin_amdgcn_s_setprio(0);
    if (t < nkt - 2)       asm volatile("s_waitcnt vmcnt(4)" ::: "memory");
    else if (t == nkt - 2) asm volatile("s_waitcnt vmcnt(0)" ::: "memory");
    __builtin_amdgcn_s_barrier();
    __builtin_amdgcn_sched_barrier(0);
    slot = (slot == 2) ? 0 : slot + 1;
  }

  // C write: identical layout to validated R4-R6 gemm_f16 epilogue
  const int row0 = blockIdx.y * 128 + wr * 64 + ((lane >> 4) << 2);
  const int col0 = blockIdx.x * 128 + wc * 64 + (lane & 15);
#pragma unroll
  for (int i = 0; i < 4; ++i)
#pragma unroll
    for (int j = 0; j < 4; ++j) {
#pragma unroll
      for (int r = 0; r < 4; ++r)
        C[(size_t)(row0 + i * 16 + r) * N + col0 + j * 16] = acc[i][j][r];
    }
}

__global__ __launch_bounds__(256)
void reduce_add(const float4* __restrict__ a, const float4* __restrict__ b,
                float4* __restrict__ o, int n4) {
  for (int i = blockIdx.x * 256 + threadIdx.x; i < n4; i += gridDim.x * 256) {
    const float4 x = a[i], y = b[i];
    o[i] = make_float4(x.x + y.x, x.y + y.y, x.z + y.z, x.w + y.w);
  }
}

// ---------------------------------------------------------------------------
// MFMA flash attention (R13, validated): staged K/V with pipelined staging.
// K single-buf + V double-buf; stage kt+64 issued at the post-QK barrier,
// drained by vmcnt(0) AFTER softmax+PV.
// ---------------------------------------------------------------------------
__global__ __launch_bounds__(256)
void attn_mfma(const _Float16* __restrict__ Qpk, const _Float16* __restrict__ Kpk,
               const _Float16* __restrict__ Vpk, _Float16* __restrict__ Ap2) {
  const int h = blockIdx.x;
  const int q0 = blockIdx.y * 128;
  const int kvh = h >> 3;
  const int tid = threadIdx.x;
  const int lane = tid & 63;
  const int wv = tid >> 6;
  const int l15 = lane & 15;
  const int l4 = lane >> 4;

  __shared__ _Float16 SM[8192 + 2 * 8192 + 4 * 32 * PSTR];
  _Float16* Ks = SM;
  _Float16* Vs = SM + 8192;            // two 8192-f16 buffers
  _Float16* Pw = SM + 24576 + wv * 32 * PSTR;

  f16x8 qfA[4], qfB[4];
  {
    const _Float16* qa = Qpk + ((size_t)h * 128 + (q0 >> 4) + wv * 2) * 2048 + lane * 8;
#pragma unroll
    for (int ds = 0; ds < 4; ++ds) {
      qfA[ds] = *(const f16x8*)(qa + ds * 512);
      qfB[ds] = *(const f16x8*)(qa + 2048 + ds * 512);
    }
  }

  f16x8 ones;
#pragma unroll
  for (int j = 0; j < 8; ++j) ones[j] = (_Float16)1.0f;

  f32x4 OA[8], OB[8];
#pragma unroll
  for (int dt = 0; dt < 8; ++dt) { OA[dt] = (f32x4)0.f; OB[dt] = (f32x4)0.f; }
  f32x4 LA = (f32x4)0.f, LB = (f32x4)0.f;

  int kstart = q0 - (WINDOW - 1);
  if (kstart < 0) kstart = 0;
  kstart &= ~63;
  const int kend = q0 + 128;

  // stage K[kt2] -> Ks, V[kt2] -> Vs[vb]  (8 gl2lds per wave)
  auto stageKV = [&](int kt2, int vb) {
    const _Float16* Kg = Kpk + ((size_t)kvh * 128 + (kt2 >> 4)) * 2048 + lane * 8;
    const _Float16* Vg = Vpk + ((size_t)kvh * 32 + (kt2 >> 6)) * 8192 + lane * 8;
#pragma unroll
    for (int t = wv; t < 16; t += 4) {
      gl2lds16(Kg + t * 512, (char*)Ks + t * 1024);
      gl2lds16(Vg + t * 512, (char*)(Vs + vb * 8192) + t * 1024);
    }
  };

  // prologue: stage first tile, drain, barrier
  stageKV(kstart, 0);
  asm volatile("s_waitcnt vmcnt(0)" ::: "memory");
  __builtin_amdgcn_s_barrier();
  __builtin_amdgcn_sched_barrier(0);

  int vbuf = 0;
  for (int kt = kstart; kt < kend; kt += 64) {
    // ---- QK^T from Ks ----
    f32x4 sA[4], sB[4];
#pragma unroll
    for (int nt = 0; nt < 4; ++nt) { sA[nt] = (f32x4)(-MLOG2E); sB[nt] = (f32x4)(-MLOG2E); }
    __builtin_amdgcn_s_setprio(1);
#pragma unroll
    for (int ds = 0; ds < 4; ++ds) {
#pragma unroll
      for (int nt = 0; nt < 4; ++nt) {
        const f16x8 kf = *(const f16x8*)(Ks + (nt * 4 + ds) * 512 + lane * 8);
        sA[nt] = __builtin_amdgcn_mfma_f32_16x16x32_f16(qfA[ds], kf, sA[nt], 0, 0, 0);
        sB[nt] = __builtin_amdgcn_mfma_f32_16x16x32_f16(qfB[ds], kf, sB[nt], 0, 0, 0);
      }
    }
    __builtin_amdgcn_s_setprio(0);
    // all waves done reading Ks -> safe to overwrite; V[kt] still live in Vs[vbuf]
    __builtin_amdgcn_s_barrier();
    __builtin_amdgcn_sched_barrier(0);
    if (kt + 64 < kend) stageKV(kt + 64, vbuf ^ 1);

    // ---- softmax -> Pw (wave-private) ----
    const int qbA = q0 + wv * 32 + l4 * 4;
    const int kb = kt + l15;
#pragma unroll
    for (int nt = 0; nt < 4; ++nt) {
      const int kidx = kb + nt * 16;
#pragma unroll
      for (int r = 0; r < 4; ++r) {
        float pA = __builtin_amdgcn_exp2f(sA[nt][r]);
        float pB = __builtin_amdgcn_exp2f(sB[nt][r]);
        pA = ((unsigned)(qbA + r - kidx) < WINDOW) ? pA : 0.f;
        pB = ((unsigned)(qbA + 16 + r - kidx) < WINDOW) ? pB : 0.f;
        Pw[(l4 * 4 + r) * PSTR + nt * 16 + l15] = (_Float16)pA;
        Pw[(16 + l4 * 4 + r) * PSTR + nt * 16 + l15] = (_Float16)pB;
      }
    }

    // ---- P @ V from Vs[vbuf] ----
    const _Float16* Vcur = Vs + vbuf * 8192;
    __builtin_amdgcn_s_setprio(1);
#pragma unroll
    for (int ks = 0; ks < 2; ++ks) {
      const f16x8 pfA = *(const f16x8*)(Pw + l15 * PSTR + ks * 32 + l4 * 8);
      const f16x8 pfB = *(const f16x8*)(Pw + (16 + l15) * PSTR + ks * 32 + l4 * 8);
      LA = __builtin_amdgcn_mfma_f32_16x16x32_f16(pfA, ones, LA, 0, 0, 0);
      LB = __builtin_amdgcn_mfma_f32_16x16x32_f16(pfB, ones, LB, 0, 0, 0);
#pragma unroll
      for (int dt = 0; dt < 8; ++dt) {
        const f16x8 vf = *(const f16x8*)(Vcur + (ks * 8 + dt) * 512 + lane * 8);
        OA[dt] = __builtin_amdgcn_mfma_f32_16x16x32_f16(pfA, vf, OA[dt], 0, 0, 0);
        OB[dt] = __builtin_amdgcn_mfma_f32_16x16x32_f16(pfB, vf, OB[dt], 0, 0, 0);
      }
    }
    __builtin_amdgcn_s_setprio(0);
    // drain this iteration's staging (covered by softmax+PV above), fence
    asm volatile("s_waitcnt vmcnt(0)" ::: "memory");
    __builtin_amdgcn_s_barrier();
    __builtin_amdgcn_sched_barrier(0);
    vbuf ^= 1;
  }

  // epilogue: Tw aliases SM[0..8704) (Ks/Vs dead; all waves past final barrier)
  _Float16* Tw = SM + wv * 16 * ESTR;
#pragma unroll
  for (int half = 0; half < 2; ++half) {
    const f32x4* O = half ? OB : OA;
    const f32x4  L = half ? LB : LA;
    float inv[4];
#pragma unroll
    for (int r = 0; r < 4; ++r) inv[r] = 1.0f / L[r];
#pragma unroll
    for (int dt = 0; dt < 8; ++dt)
#pragma unroll
      for (int r = 0; r < 4; ++r)
        Tw[(l4 * 4 + r) * ESTR + dt * 16 + l15] = (_Float16)(O[dt][r] * inv[r]);
    const int qt = (q0 >> 4) + wv * 2 + half;
#pragma unroll
    for (int ds = 0; ds < 4; ++ds) {
      const f16x8 frag = *(const f16x8*)(Tw + l15 * ESTR + ds * 32 + l4 * 8);
      *(f16x8*)(Ap2 + ((size_t)(h * 4 + ds) * 128 + qt) * 512 + lane * 8) = frag;
    }
  }
}

// ---------------------------------------------------------------------------
// Launch (5 dispatches)
// ---------------------------------------------------------------------------
extern "C" void kernel_launch(void* const* d_in, const int* in_sizes, int n_in,
                              void* d_out, int out_size, void* d_ws, size_t ws_size,
                              hipStream_t stream) {
  const int*   positions = (const int*)d_in[0];
  const float* hidden    = (const float*)d_in[1];
  const float* w_qkv     = (const float*)d_in[2];
  const float* w_o       = (const float*)d_in[3];
  const float* q_norm_w  = (const float*)d_in[4];
  const float* k_norm_w  = (const float*)d_in[5];
  float* out = (float*)d_out;

  // workspace (same 139.5 MB footprint as R6)
  char* ws = (char*)d_ws;
  _Float16* Kpk = (_Float16*)ws;                    // 2.1 MB
  _Float16* Vpk = Kpk + (size_t)T * NKV * D;        // 2.1 MB
  ws += (size_t)T * QKVW * 4;
  _Float16* Ap2 = (_Float16*)ws;                    // 16.8 MB
  float* P0 = (float*)(ws + (size_t)T * ODIM * 2);  // 16.8 MB
  ws += (size_t)T * ODIM * 4;
  float* cosT = (float*)ws;  ws += (size_t)T * 64 * 4;
  float* sinT = (float*)ws;  ws += (size_t)T * 64 * 4;
  _Float16* Bp1 = (_Float16*)ws; ws += (size_t)HIDDEN * QKVW * 2;  // 21.0 MB
  _Float16* Bp2 = (_Float16*)ws; ws += (size_t)ODIM * HIDDEN * 2;  // 16.8 MB
  _Float16* Ah1 = (_Float16*)ws; ws += (size_t)T * HIDDEN * 2;     // 8.4 MB
  _Float16* Qpk = (_Float16*)ws;                    // dead after attn
  float* P1 = (float*)Qpk;                          // alias: written after attn
  ws += (size_t)T * ODIM * 2;

  // 0) all packing + RoPE tables in one dispatch (coalesced B-packs)
  prep<<<dim3(NB_A + NB_B1 + NB_B2 + T / 64), 256, 0, stream>>>(
      hidden, w_qkv, w_o, positions, Ah1, Bp1, Bp2, cosT, sinT);

  // 1) fused qkv GEMM + RMSNorm/RoPE/pack (ring-3, identity mapping)
  gemm_qkv<<<dim3(QKVW / 128, T / 128), 256, 49152, stream>>>(
      Ah1, Bp1, q_norm_w, k_norm_w, cosT, sinT, Qpk, Kpk, Vpk);

  // 2) MFMA flash attention (pipelined staged K/V) -> Ap2
  attn_mfma<<<dim3(NH, T / 128), 256, 0, stream>>>(Qpk, Kpk, Vpk, Ap2);

  // 3) out = attn @ w_o, split-K=2 (ring-3, identity mapping), then reduce
  gemm_f16p<<<dim3(HIDDEN / 128, T / 128, 2), 256, 49152, stream>>>(
      Ap2, Bp2, P0, P1, T, HIDDEN, ODIM / 32 / 2);
  reduce_add<<<dim3(1024), 256, 0, stream>>>((const float4*)P0, (const float4*)P1,
                                             (float4*)out, T * HIDDEN / 4);
}